// Round 21
// baseline (142.721 us; speedup 1.0000x reference)
//
#include <hip/hip_runtime.h>

// HellingerDistance: out[n][m] = 0.5*(rowsum_a[n] + rowsum_b[m]) - sqrt(a[n])·sqrt(b[m])
// N = M = 8192, D = 1024, f32 in/out.
// Round 21: i8 TLP GEMM. 128x128 tile, BK=128, 4 waves, single 32KB LDS buffer,
// plain __syncthreads() 2-barrier loop (compiler-scheduled waits), 3 blocks/CU
// co-resident -> cross-block DS/MFMA overlap (m114) replaces manual pipelining.
// i8 makes DS traffic small and MFMA fast; QA/QB (16MB) fully L3-resident.

#define NM 8192
#define DD 1024

typedef __attribute__((ext_vector_type(4))) int i32x4;
typedef __attribute__((ext_vector_type(16))) int i32x16;
typedef __attribute__((ext_vector_type(8))) short bf16x8;
typedef __attribute__((ext_vector_type(4))) float f32x4;

#define AS1 __attribute__((address_space(1)))
#define AS3 __attribute__((address_space(3)))

// f32 -> bf16 round-to-nearest-even (fallback kernel only)
static __device__ __forceinline__ unsigned short f2bf(float f) {
  unsigned int u = __float_as_uint(f);
  u += 0x7FFFu + ((u >> 16) & 1u);
  return (unsigned short)(u >> 16);
}

// ---------------- kernel 1: sqrt -> i8 (x127), exact f32 rowsums -----------
__global__ __launch_bounds__(256)
void hell_prep8(const float* __restrict__ A, const float* __restrict__ B,
                signed char* __restrict__ QA, signed char* __restrict__ QB,
                float* __restrict__ RA, float* __restrict__ RB) {
  __shared__ float wsum[4];
  const int row = blockIdx.x & (NM - 1);
  const bool isB = blockIdx.x >= NM;
  const float* src = (isB ? B : A) + (size_t)row * DD;
  signed char* dst = (isB ? QB : QA) + (size_t)row * DD;
  const int t = threadIdx.x;
  const float4 v = ((const float4*)src)[t];
  char4 q;
  q.x = (signed char)__float2int_rn(sqrtf(v.x) * 127.0f);
  q.y = (signed char)__float2int_rn(sqrtf(v.y) * 127.0f);
  q.z = (signed char)__float2int_rn(sqrtf(v.z) * 127.0f);
  q.w = (signed char)__float2int_rn(sqrtf(v.w) * 127.0f);
  ((char4*)dst)[t] = q;
  float s = (v.x + v.y) + (v.z + v.w);
#pragma unroll
  for (int m = 1; m < 64; m <<= 1) s += __shfl_xor(s, m, 64);
  if ((t & 63) == 0) wsum[t >> 6] = s;
  __syncthreads();
  if (t == 0) (isB ? RB : RA)[row] = wsum[0] + wsum[1] + wsum[2] + wsum[3];
}

// ---------------- kernel 2: 128^2 i8 TLP GEMM, BK=128 ----------------------
// LDS: As [128 rows][128 k] i8 (128B/row = 8 chunks) at +0 (16KB), Bs at
// +16384. Chunk c of row r stored at c ^ (r&7) (both-sides swizzle:
// pre-swizzled global source + XOR'd read slot).
__global__ __launch_bounds__(256, 3)
void hell_gemm20(const signed char* __restrict__ QA,
                 const signed char* __restrict__ QB,
                 const float* __restrict__ RA, const float* __restrict__ RB,
                 float* __restrict__ C) {
  __shared__ __attribute__((aligned(16))) char lds[32768];

  const int t = threadIdx.x;
  const int lane = t & 63;
  const int wave = t >> 6;
  const int wrow = (wave >> 1) * 64;  // 0..1 -> rows
  const int wcol = (wave & 1) * 64;   // 0..1 -> cols

  // bijective XCD swizzle: nwg = 4096, 8 XCDs, chunk = 512
  const int wg = blockIdx.x;
  const int s = (wg & 7) * 512 + (wg >> 3);
  const int brow = (s >> 6) * 128;
  const int bcol = (s & 63) * 128;

  // staging: thread t covers rows (t>>3)+i*32, chunk t&7; source pre-swizzled
  const int sw = (t & 7) ^ ((t >> 3) & 7);

  const int kg = lane >> 5;   // k-group (0..1)
  const int lo5 = lane & 31;  // row/col within 32
  const int x7 = lo5 & 7;

  // read slot byte offsets for the 4 k-steps: ((ks*2+kg)^x7)<<4
  int slot[4];
#pragma unroll
  for (int ks = 0; ks < 4; ++ks) slot[ks] = (((ks * 2 + kg) ^ x7) << 4);

  const char* aB = lds + (wrow + lo5) * 128;          // +m*32*128 for m-tile
  const char* bB = lds + 16384 + (wcol + lo5) * 128;  // +n*32*128 for n-tile

  i32x16 acc[2][2];  // 4 x 32x32 accum tiles = 64 regs
#pragma unroll
  for (int m = 0; m < 2; ++m)
#pragma unroll
    for (int n = 0; n < 2; ++n)
#pragma unroll
      for (int r = 0; r < 16; ++r) acc[m][n][r] = 0;

  const signed char* gA = QA + (size_t)(brow + (t >> 3)) * DD + sw * 16;
  const signed char* gB = QB + (size_t)(bcol + (t >> 3)) * DD + sw * 16;

#pragma unroll 1
  for (int kt = 0; kt < DD / 128; ++kt) {
    // stage A (16KB) + B (16KB): 8 gloads/thread, linear LDS dest
#pragma unroll
    for (int i = 0; i < 4; ++i)
      __builtin_amdgcn_global_load_lds(
          (const AS1 unsigned int*)(gA + (size_t)(i * 32) * DD + kt * 128),
          (AS3 unsigned int*)(lds + i * 4096 + t * 16), 16, 0, 0);
#pragma unroll
    for (int i = 0; i < 4; ++i)
      __builtin_amdgcn_global_load_lds(
          (const AS1 unsigned int*)(gB + (size_t)(i * 32) * DD + kt * 128),
          (AS3 unsigned int*)(lds + 16384 + i * 4096 + t * 16), 16, 0, 0);
    __syncthreads();  // compiler drains vmcnt; co-resident blocks hide it

#pragma unroll
    for (int ks = 0; ks < 4; ++ks) {
      i32x4 af[2], bf2[2];
#pragma unroll
      for (int m = 0; m < 2; ++m)
        af[m] = *(const i32x4*)(aB + m * 4096 + slot[ks]);
#pragma unroll
      for (int n = 0; n < 2; ++n)
        bf2[n] = *(const i32x4*)(bB + n * 4096 + slot[ks]);
#pragma unroll
      for (int m = 0; m < 2; ++m)
#pragma unroll
        for (int n = 0; n < 2; ++n)
          acc[m][n] = __builtin_amdgcn_mfma_i32_32x32x32_i8(af[m], bf2[n],
                                                            acc[m][n], 0, 0, 0);
    }
    __syncthreads();  // all reads done before next stage overwrites
  }

  // epilogue: 32x32 C/D layout col=lane&31, row=(r&3)+8*(r>>2)+4*(lane>>5)
  const float inv = 1.0f / 16129.0f;  // 1/127^2
  float hrb[2];
#pragma unroll
  for (int n = 0; n < 2; ++n)
    hrb[n] = 0.5f * RB[bcol + wcol + n * 32 + lo5];
#pragma unroll
  for (int m = 0; m < 2; ++m) {
#pragma unroll
    for (int r = 0; r < 16; ++r) {
      const int row = (r & 3) + 8 * (r >> 2) + 4 * kg;
      const int R = wrow + m * 32 + row;
      const float ha = 0.5f * RA[brow + R];
      float* orow = C + (size_t)(brow + R) * NM + bcol;
#pragma unroll
      for (int n = 0; n < 2; ++n)
        orow[wcol + n * 32 + lo5] = ha + hrb[n] - (float)acc[m][n][r] * inv;
    }
  }
}

// ---------------- fallback: bf16 fused kernel (if ws too small) ------------
static __device__ __forceinline__ int swz(int row, int colbytes) {
  return (row * 128 + colbytes) ^ ((row & 7) << 4);
}

__global__ __launch_bounds__(256, 2)
void hellinger_fused(const float* __restrict__ A, const float* __restrict__ B,
                     float* __restrict__ C) {
  __shared__ unsigned short As[128 * 64];
  __shared__ unsigned short Bs[128 * 64];
  __shared__ float sA[128];
  __shared__ float sB[128];

  const int t = threadIdx.x;
  const int lane = t & 63;
  const int wave = t >> 6;
  const int wrow = (wave >> 1) * 64;
  const int wcol = (wave & 1) * 64;
  const int brow = blockIdx.y * 128;
  const int bcol = blockIdx.x * 128;
  const int sr = t >> 4;
  const int sc = (t & 15) * 4;

  const float* ap = A + (size_t)(brow + sr) * DD + sc;
  const float* bp = B + (size_t)(bcol + sr) * DD + sc;

  float racc[8], cacc[8];
#pragma unroll
  for (int i = 0; i < 8; ++i) { racc[i] = 0.f; cacc[i] = 0.f; }

  f32x4 acc[4][4];
#pragma unroll
  for (int m = 0; m < 4; ++m)
#pragma unroll
    for (int n = 0; n < 4; ++n) acc[m][n] = (f32x4){0.f, 0.f, 0.f, 0.f};

  for (int kt = 0; kt < DD / 64; ++kt) {
#pragma unroll
    for (int i = 0; i < 8; ++i) {
      const float4 v = *(const float4*)(ap + (size_t)(i * 16) * DD + kt * 64);
      racc[i] += (v.x + v.y) + (v.z + v.w);
      ushort4 p;
      p.x = f2bf(sqrtf(v.x)); p.y = f2bf(sqrtf(v.y));
      p.z = f2bf(sqrtf(v.z)); p.w = f2bf(sqrtf(v.w));
      *(ushort4*)((char*)As + swz(i * 16 + sr, sc * 2)) = p;
    }
#pragma unroll
    for (int i = 0; i < 8; ++i) {
      const float4 v = *(const float4*)(bp + (size_t)(i * 16) * DD + kt * 64);
      cacc[i] += (v.x + v.y) + (v.z + v.w);
      ushort4 p;
      p.x = f2bf(sqrtf(v.x)); p.y = f2bf(sqrtf(v.y));
      p.z = f2bf(sqrtf(v.z)); p.w = f2bf(sqrtf(v.w));
      *(ushort4*)((char*)Bs + swz(i * 16 + sr, sc * 2)) = p;
    }
    __syncthreads();
#pragma unroll
    for (int kk = 0; kk < 2; ++kk) {
      const int koffb = kk * 64 + (lane >> 4) * 16;
      bf16x8 af[4], bfr[4];
#pragma unroll
      for (int m = 0; m < 4; ++m)
        af[m] = *(const bf16x8*)((const char*)As + swz(wrow + m * 16 + (lane & 15), koffb));
#pragma unroll
      for (int n = 0; n < 4; ++n)
        bfr[n] = *(const bf16x8*)((const char*)Bs + swz(wcol + n * 16 + (lane & 15), koffb));
#pragma unroll
      for (int m = 0; m < 4; ++m)
#pragma unroll
        for (int n = 0; n < 4; ++n)
          acc[m][n] = __builtin_amdgcn_mfma_f32_16x16x32_bf16(af[m], bfr[n], acc[m][n], 0, 0, 0);
    }
    __syncthreads();
  }

#pragma unroll
  for (int i = 0; i < 8; ++i) {
#pragma unroll
    for (int mask = 1; mask < 16; mask <<= 1) {
      racc[i] += __shfl_xor(racc[i], mask, 64);
      cacc[i] += __shfl_xor(cacc[i], mask, 64);
    }
  }
  if ((t & 15) == 0) {
#pragma unroll
    for (int i = 0; i < 8; ++i) { sA[i * 16 + sr] = racc[i]; sB[i * 16 + sr] = cacc[i]; }
  }
  __syncthreads();

#pragma unroll
  for (int m = 0; m < 4; ++m) {
    const int rbase = wrow + m * 16 + (lane >> 4) * 4;
#pragma unroll
    for (int j = 0; j < 4; ++j) {
      const int row = rbase + j;
      const float ha = 0.5f * sA[row];
      float* orow = C + (size_t)(brow + row) * NM + bcol;
#pragma unroll
      for (int n = 0; n < 4; ++n) {
        const int col = wcol + n * 16 + (lane & 15);
        orow[col] = ha + 0.5f * sB[col] - acc[m][n][j];
      }
    }
  }
}

extern "C" void kernel_launch(void* const* d_in, const int* in_sizes, int n_in,
                              void* d_out, int out_size, void* d_ws, size_t ws_size,
                              hipStream_t stream) {
  const float* a = (const float*)d_in[0];
  const float* b = (const float*)d_in[1];
  float* out = (float*)d_out;

  const size_t mat_bytes = (size_t)NM * DD;  // 8 MB per i8 matrix
  const size_t need = 2 * mat_bytes + 2 * (size_t)NM * sizeof(float);

  if (ws_size >= need) {
    signed char* QA = (signed char*)d_ws;
    signed char* QB = (signed char*)d_ws + mat_bytes;
    float* RA = (float*)((char*)d_ws + 2 * mat_bytes);
    float* RB = RA + NM;
    hipLaunchKernelGGL(hell_prep8, dim3(2 * NM), dim3(256), 0, stream,
                       a, b, QA, QB, RA, RB);
    hipLaunchKernelGGL(hell_gemm20, dim3(64 * 64), dim3(256), 0, stream,
                       QA, QB, RA, RB, out);
  } else {
    dim3 grid(NM / 128, NM / 128);
    hipLaunchKernelGGL(hellinger_fused, grid, dim3(256), 0, stream, a, b, out);
  }
}